// Round 5
// baseline (1628.445 us; speedup 1.0000x reference)
//
#include <hip/hip_runtime.h>
#include <math.h>

#define N_TOK 32768
#define DIM   256
#define KCODE 4096

// ---- workspace layout (float offsets) ----
#define WS_E2      0                      // [4096]
#define WS_COUNTS  4096                   // [4096]
#define WS_LOSSP   8192                   // [256]
#define WS_SCAL    8448                   // [64]  scal[0]=bias
#define WS_CNORM   8512                   // [4096]
#define WS_IDX     12608                  // int [32768]
#define WS_EHS     307520                 // fp16 planes [2][16][8][256][32] = 4 MB (exact fit)
#define WS_DWT     1356096                // dwT [4096*256]

// ---- output layout (float offsets) ----
#define OUT_Q      0
#define OUT_LOSS   8388608
#define OUT_PERP   8388609
#define OUT_IDX    8388610
#define OUT_EMB    8421378

#define EH_PLANE   1048576                // halves per eh plane
#define XH_PLANE   8388608                // halves per xh plane

typedef _Float16 f16x8 __attribute__((ext_vector_type(8)));
typedef _Float16 f16x4 __attribute__((ext_vector_type(4)));
typedef float    f32x4 __attribute__((ext_vector_type(4)));

// ||e_k||^2, partials over d with atomics (e2 pre-zeroed)
__global__ void k_e2(const float* __restrict__ emb, float* __restrict__ e2)
{
    int k  = blockIdx.x * 256 + threadIdx.x;
    int d0 = blockIdx.y * 32;
    float s = 0.0f;
#pragma unroll 8
    for (int d = 0; d < 32; ++d) {
        float v = emb[(size_t)(d0 + d) * KCODE + k];
        s += v * v;
    }
    atomicAdd(&e2[k], s);
}

// x [N][D] -> split fp16 planes xh[2][N][D] (stored in d_out OUT_Q region)
__global__ void k_split_x(const float* __restrict__ x, unsigned short* __restrict__ xh)
{
    int i = (blockIdx.x * 256 + threadIdx.x) * 8;
    float4 f0 = *(const float4*)(x + i);
    float4 f1 = *(const float4*)(x + i + 4);
    float fv[8] = {f0.x, f0.y, f0.z, f0.w, f1.x, f1.y, f1.z, f1.w};
    f16x8 h1, h2;
#pragma unroll
    for (int j = 0; j < 8; ++j) {
        _Float16 a = (_Float16)fv[j];
        h1[j] = a;
        h2[j] = (_Float16)(fv[j] - (float)a);
    }
    *(f16x8*)((_Float16*)xh + i)            = h1;
    *(f16x8*)((_Float16*)xh + XH_PLANE + i) = h2;
}

// emb [D][K] -> pre-tiled split planes ehs[p][ct][ks][code&255][d&31]
__global__ void k_split_e(const float* __restrict__ emb, unsigned short* __restrict__ ehs_)
{
    __shared__ float tile[32][33];
    _Float16* ehs = (_Float16*)ehs_;
    int t  = threadIdx.x;
    int tx = t & 31, iy = t >> 5;
    int k0 = blockIdx.x * 32, d0 = blockIdx.y * 32;
#pragma unroll
    for (int j = 0; j < 4; ++j)
        tile[iy + 8 * j][tx] = emb[(size_t)(d0 + iy + 8 * j) * KCODE + k0 + tx];
    __syncthreads();
    // tile[d_off][k_off]; this thread emits code = k0+tx, d = d0 + iy*4 .. +3
    int code = k0 + tx;
    size_t base = (size_t)(((code >> 8) * 8) + (d0 >> 5)) * 8192 + (code & 255) * 32 + iy * 4;
    f16x4 h1, h2;
#pragma unroll
    for (int j = 0; j < 4; ++j) {
        float v = tile[iy * 4 + j][tx];   // FIX: d index first, code index second
        _Float16 a = (_Float16)v;
        h1[j] = a;
        h2[j] = (_Float16)(v - (float)a);
    }
    *(f16x4*)(ehs + base)            = h1;
    *(f16x4*)(ehs + EH_PLANE + base) = h2;
}

// Argmin over codes via fp16x2-split MFMA, precomputed planes.
// Block: 32 rows x full 4096 codes in 16 tiles of 256. Wave w owns 64 codes/tile.
__global__ __launch_bounds__(256, 2)
void k_argmin(const unsigned short* __restrict__ xh_, const unsigned short* __restrict__ ehs_,
              const float* __restrict__ e2, int* __restrict__ idx_out)
{
    __shared__ __align__(16) _Float16 Ah[2][32][256];   // x planes, XOR-swizzled 8-elem groups
    __shared__ __align__(16) _Float16 Bh[2][256][40];   // code k-slice planes (32 k + 8 pad)
    __shared__ float e2s[256];

    const _Float16* xh  = (const _Float16*)xh_;
    const _Float16* ehs = (const _Float16*)ehs_;

    const int t    = threadIdx.x;
    const int lane = t & 63, w = t >> 6;
    const int lo   = lane & 15, q = lane >> 4;
    const int row0 = blockIdx.x * 32;

    // ---- prologue: stage A planes from xh ----
    {
        int m = t >> 3, kb = (t & 7) * 32;
#pragma unroll
        for (int p = 0; p < 2; ++p) {
            const _Float16* src = xh + (size_t)p * XH_PLANE + (size_t)(row0 + m) * DIM + kb;
#pragma unroll
            for (int g = 0; g < 4; ++g) {
                f16x8 h = *(const f16x8*)(src + g * 8);
                int grp = ((kb >> 3) + g) ^ (m & 7);
                *(f16x8*)&Ah[p][m][grp * 8] = h;
            }
        }
    }

    float best[8];
    int   bidx[8];
#pragma unroll
    for (int s = 0; s < 8; ++s) { best[s] = 3.4e38f; bidx[s] = 0; }

    // staging role: wave -> (plane, code-half); lane -> 2 codes (128 B contiguous)
    const int sp = w & 1, sh = w >> 1;
    const _Float16* ehp = ehs + (size_t)sp * EH_PLANE + sh * 4096 + lane * 64;
    const int jrot = lane >> 2;

    uint4 pf[8];
#pragma unroll
    for (int j = 0; j < 8; ++j) pf[j] = *(const uint4*)(ehp + j * 8);

    for (int ct = 0; ct < 16; ++ct) {
        f32x4 acc[2][4];
#pragma unroll
        for (int mf = 0; mf < 2; ++mf)
#pragma unroll
            for (int nf = 0; nf < 4; ++nf) acc[mf][nf] = (f32x4)0.0f;

        for (int ks = 0; ks < 8; ++ks) {
            __syncthreads();   // previous slice fully consumed
            // write staged slice (write-order rotated for bank uniformity)
#pragma unroll
            for (int i = 0; i < 2; ++i)
#pragma unroll
                for (int jj = 0; jj < 4; ++jj) {
                    int j = (jj + jrot) & 3;
                    *(uint4*)&Bh[sp][sh * 128 + 2 * lane + i][j * 8] = pf[i * 4 + j];
                }
            if (ks == 0 && t < 64)
                *(float4*)&e2s[t * 4] = *(const float4*)&e2[ct * 256 + t * 4];
            __syncthreads();

            // prefetch next slice (overlaps with MFMA below)
            int nit = ct * 8 + ks + 1;
            if (nit < 128) {
                const _Float16* src = ehp + (size_t)nit * 8192;
#pragma unroll
                for (int j = 0; j < 8; ++j) pf[j] = *(const uint4*)(src + j * 8);
            }

            // A fragments (shared across nf)
            int agrp = ((ks * 4 + q) ^ (lo & 7)) * 8;
            f16x8 a1_0 = *(const f16x8*)&Ah[0][lo][agrp];
            f16x8 a2_0 = *(const f16x8*)&Ah[1][lo][agrp];
            f16x8 a1_1 = *(const f16x8*)&Ah[0][lo + 16][agrp];
            f16x8 a2_1 = *(const f16x8*)&Ah[1][lo + 16][agrp];

#pragma unroll
            for (int nf = 0; nf < 4; ++nf) {
                int crow = w * 64 + nf * 16 + lo;
                f16x8 b1 = *(const f16x8*)&Bh[0][crow][q * 8];
                f16x8 b2 = *(const f16x8*)&Bh[1][crow][q * 8];
                acc[0][nf] = __builtin_amdgcn_mfma_f32_16x16x32_f16(a2_0, b1, acc[0][nf], 0, 0, 0);
                acc[1][nf] = __builtin_amdgcn_mfma_f32_16x16x32_f16(a2_1, b1, acc[1][nf], 0, 0, 0);
                acc[0][nf] = __builtin_amdgcn_mfma_f32_16x16x32_f16(a1_0, b2, acc[0][nf], 0, 0, 0);
                acc[1][nf] = __builtin_amdgcn_mfma_f32_16x16x32_f16(a1_1, b2, acc[1][nf], 0, 0, 0);
                acc[0][nf] = __builtin_amdgcn_mfma_f32_16x16x32_f16(a1_0, b1, acc[0][nf], 0, 0, 0);
                acc[1][nf] = __builtin_amdgcn_mfma_f32_16x16x32_f16(a1_1, b1, acc[1][nf], 0, 0, 0);
            }
        }

        // fold: dist = e2 - 2*score (x^2 row-constant dropped). codes ascending.
#pragma unroll
        for (int mf = 0; mf < 2; ++mf)
#pragma unroll
            for (int nf = 0; nf < 4; ++nf)
#pragma unroll
                for (int r = 0; r < 4; ++r) {
                    int cl = w * 64 + nf * 16 + lo;
                    float dist = fmaf(-2.0f, acc[mf][nf][r], e2s[cl]);
                    int s = mf * 4 + r;
                    if (dist < best[s]) { best[s] = dist; bidx[s] = ct * 256 + cl; }
                }
    }

    // ---- final argmin reduction across lanes (scratch overlays Ah) ----
    __syncthreads();
    float* rv = (float*)&Ah[0][0][0];
    int*   ri = (int*)(((char*)&Ah[0][0][0]) + 8192);
#pragma unroll
    for (int s = 0; s < 8; ++s) {
        int row = (s >> 2) * 16 + q * 4 + (s & 3);
        rv[row * 64 + w * 16 + lo] = best[s];
        ri[row * 64 + w * 16 + lo] = bidx[s];
    }
    __syncthreads();
    if (t < 32) {
        float bv = rv[t * 64];
        int   bi = ri[t * 64];
        for (int j = 1; j < 64; ++j) {
            float v = rv[t * 64 + j];
            int  ii = ri[t * 64 + j];
            if (v < bv || (v == bv && ii < bi)) { bv = v; bi = ii; }
        }
        idx_out[row0 + t] = bi;
    }
}

// one wave per row: quantized copy (reconstructed from planes), loss, counts, dwT, idx
__global__ void k_gather(const float* __restrict__ x, const unsigned short* __restrict__ ehs_,
                         const int* __restrict__ idx, float* __restrict__ out_q,
                         float* __restrict__ out_idxf, float* __restrict__ counts,
                         float* __restrict__ dwT, float* __restrict__ lossp)
{
    const _Float16* ehs = (const _Float16*)ehs_;
    int t = threadIdx.x;
    int lane = t & 63, w = t >> 6;
    int n = blockIdx.x * 4 + w;
    int k = idx[n];
    float4 xv = *(const float4*)&x[(size_t)n * DIM + lane * 4];
    // d = lane*4..+3 -> ks = lane>>3, kk = (lane&7)*4
    size_t base = (size_t)(((k >> 8) * 8) + (lane >> 3)) * 8192 + (k & 255) * 32 + (lane & 7) * 4;
    f16x4 h1 = *(const f16x4*)(ehs + base);
    f16x4 h2 = *(const f16x4*)(ehs + EH_PLANE + base);
    float4 ev;
    ev.x = (float)h1[0] + (float)h2[0];
    ev.y = (float)h1[1] + (float)h2[1];
    ev.z = (float)h1[2] + (float)h2[2];
    ev.w = (float)h1[3] + (float)h2[3];
    *(float4*)&out_q[(size_t)n * DIM + lane * 4] = ev;
    float dx = ev.x - xv.x, dy = ev.y - xv.y, dz = ev.z - xv.z, dw = ev.w - xv.w;
    float s = dx * dx + dy * dy + dz * dz + dw * dw;
#pragma unroll
    for (int off = 32; off > 0; off >>= 1) s += __shfl_down(s, off, 64);
    float* dp = &dwT[(size_t)k * DIM + lane * 4];
    atomicAdd(dp + 0, xv.x);
    atomicAdd(dp + 1, xv.y);
    atomicAdd(dp + 2, xv.z);
    atomicAdd(dp + 3, xv.w);
    if (lane == 0) {
        atomicAdd(&counts[k], 1.0f);
        atomicAdd(&lossp[blockIdx.x & 255], s);
        out_idxf[n] = (float)k;
    }
}

__global__ void k_finalize(const float* __restrict__ counts, const float* __restrict__ lossp,
                           const float* __restrict__ ema_counter,
                           const float* __restrict__ ema_cluster,
                           float* __restrict__ cnorm, float* __restrict__ scal,
                           float* __restrict__ out)
{
    __shared__ float red[256];
    int t = threadIdx.x;
    float ls = lossp[t];
    float ent = 0.0f, casum = 0.0f;
    float ca[16];
#pragma unroll
    for (int j = 0; j < 16; ++j) {
        int k = j * 256 + t;
        float c = counts[k];
        float p = c * (1.0f / 32768.0f);
        ent += p * logf(p + 1e-10f);
        ca[j] = ema_cluster[k] * 0.99f + c * 0.01f;   // cluster_hidden
        casum += ca[j];
    }
    red[t] = ls; __syncthreads();
    for (int o = 128; o > 0; o >>= 1) { if (t < o) red[t] += red[t + o]; __syncthreads(); }
    float loss_tot = red[0]; __syncthreads();
    red[t] = ent; __syncthreads();
    for (int o = 128; o > 0; o >>= 1) { if (t < o) red[t] += red[t + o]; __syncthreads(); }
    float ent_tot = red[0]; __syncthreads();
    red[t] = casum; __syncthreads();
    for (int o = 128; o > 0; o >>= 1) { if (t < o) red[t] += red[t + o]; __syncthreads(); }
    float casum_tot = red[0]; __syncthreads();

    float bias = 1.0f - powf(0.99f, ema_counter[0] + 1.0f);
    float n = casum_tot / bias;                 // sum(cluster_avg)
    float inv = n / (n + 4096.0f * 1e-5f);
#pragma unroll
    for (int j = 0; j < 16; ++j) {
        int k = j * 256 + t;
        cnorm[k] = (ca[j] / bias + 1e-5f) * inv;
    }
    if (t == 0) {
        out[OUT_LOSS] = 1.25f * loss_tot * (1.0f / (32768.0f * 256.0f));
        out[OUT_PERP] = expf(-ent_tot);
        scal[0] = bias;
    }
}

// new_embeddings[d][k] = (ema_dw*DECAY + dwT^T*(1-DECAY))/bias / cnorm[k]
__global__ void k_newemb(const float* __restrict__ dwT, const float* __restrict__ ema_dw,
                         const float* __restrict__ cnorm, const float* __restrict__ scal,
                         float* __restrict__ out_emb)
{
    __shared__ float tile[32][33];
    int t = threadIdx.x;
    int tx = t & 31, iy = t >> 5;
    int k0 = blockIdx.x * 32, d0 = blockIdx.y * 32;
#pragma unroll
    for (int j = 0; j < 4; ++j)
        tile[iy + 8 * j][tx] = dwT[(size_t)(k0 + iy + 8 * j) * DIM + d0 + tx];
    __syncthreads();
    float inv_bias = 1.0f / scal[0];
    float cn = cnorm[k0 + tx];
#pragma unroll
    for (int j = 0; j < 4; ++j) {
        int d = d0 + iy + 8 * j;
        float dwv = tile[tx][iy + 8 * j];
        float hid = ema_dw[(size_t)d * KCODE + k0 + tx] * 0.99f + dwv * 0.01f;
        out_emb[(size_t)d * KCODE + k0 + tx] = hid * inv_bias / cn;
    }
}

extern "C" void kernel_launch(void* const* d_in, const int* in_sizes, int n_in,
                              void* d_out, int out_size, void* d_ws, size_t ws_size,
                              hipStream_t stream)
{
    const float* x           = (const float*)d_in[0];
    const float* emb         = (const float*)d_in[1];
    const float* ema_counter = (const float*)d_in[2];
    const float* ema_cluster = (const float*)d_in[3];
    const float* ema_dw      = (const float*)d_in[4];
    float* out = (float*)d_out;
    float* ws  = (float*)d_ws;

    float* e2     = ws + WS_E2;
    float* counts = ws + WS_COUNTS;
    float* lossp  = ws + WS_LOSSP;
    float* scal   = ws + WS_SCAL;
    float* cnorm  = ws + WS_CNORM;
    int*   idxw   = (int*)(ws + WS_IDX);
    unsigned short* ehs = (unsigned short*)(ws + WS_EHS);
    float* dwT    = ws + WS_DWT;
    unsigned short* xh = (unsigned short*)(out + OUT_Q);  // scratch, overwritten by k_gather

    // zero: e2 + counts + loss partials + scalars, and dwT accumulator
    hipMemsetAsync(e2, 0, (size_t)WS_CNORM * sizeof(float), stream);
    hipMemsetAsync(dwT, 0, (size_t)KCODE * DIM * sizeof(float), stream);

    k_e2<<<dim3(16, 8), 256, 0, stream>>>(emb, e2);
    k_split_e<<<dim3(128, 8), 256, 0, stream>>>(emb, ehs);
    k_split_x<<<4096, 256, 0, stream>>>(x, xh);
    k_argmin<<<1024, 256, 0, stream>>>(xh, ehs, e2, idxw);
    k_gather<<<8192, 256, 0, stream>>>(x, ehs, idxw, out + OUT_Q, out + OUT_IDX,
                                       counts, dwT, lossp);
    k_finalize<<<1, 256, 0, stream>>>(counts, lossp, ema_counter, ema_cluster,
                                      cnorm, scal, out);
    k_newemb<<<dim3(128, 8), 256, 0, stream>>>(dwT, ema_dw, cnorm, scal, out + OUT_EMB);
}

// Round 6
// 626.443 us; speedup vs baseline: 2.5995x; 2.5995x over previous
//
#include <hip/hip_runtime.h>
#include <math.h>

#define N_TOK 32768
#define DIM   256
#define KCODE 4096

// ---- workspace layout (float offsets) ----
#define WS_E2      0                      // [4096]
#define WS_COUNTS  4096                   // [4096]
#define WS_LOSSP   8192                   // [256]
#define WS_SCAL    8448                   // [64]  scal[0]=bias
#define WS_CNORM   8512                   // [4096]
#define WS_IDX     12608                  // int [32768]
#define WS_EHS     307520                 // fp16 planes [2][16][8][256][32] = 4 MB
#define WS_DWT     1356096                // dwT [4096*256]

// ---- output layout (float offsets) ----
#define OUT_Q      0
#define OUT_LOSS   8388608
#define OUT_PERP   8388609
#define OUT_IDX    8388610
#define OUT_EMB    8421378

#define EH_PLANE   1048576                // halves per eh plane
#define XH_PLANE   8388608                // halves per xh plane

typedef _Float16 f16x8 __attribute__((ext_vector_type(8)));
typedef _Float16 f16x4 __attribute__((ext_vector_type(4)));
typedef float    f32x4 __attribute__((ext_vector_type(4)));

// ||e_k||^2, partials over d with atomics (e2 pre-zeroed)
__global__ void k_e2(const float* __restrict__ emb, float* __restrict__ e2)
{
    int k  = blockIdx.x * 256 + threadIdx.x;
    int d0 = blockIdx.y * 32;
    float s = 0.0f;
#pragma unroll 8
    for (int d = 0; d < 32; ++d) {
        float v = emb[(size_t)(d0 + d) * KCODE + k];
        s += v * v;
    }
    atomicAdd(&e2[k], s);
}

// x [N][D] -> split fp16 planes xh[2][N][D] (stored in d_out OUT_Q region)
__global__ void k_split_x(const float* __restrict__ x, unsigned short* __restrict__ xh)
{
    int i = (blockIdx.x * 256 + threadIdx.x) * 8;
    float4 f0 = *(const float4*)(x + i);
    float4 f1 = *(const float4*)(x + i + 4);
    float fv[8] = {f0.x, f0.y, f0.z, f0.w, f1.x, f1.y, f1.z, f1.w};
    f16x8 h1, h2;
#pragma unroll
    for (int j = 0; j < 8; ++j) {
        _Float16 a = (_Float16)fv[j];
        h1[j] = a;
        h2[j] = (_Float16)(fv[j] - (float)a);
    }
    *(f16x8*)((_Float16*)xh + i)            = h1;
    *(f16x8*)((_Float16*)xh + XH_PLANE + i) = h2;
}

// emb [D][K] -> pre-tiled split planes ehs[p][ct][ks][code&255][d&31]
__global__ void k_split_e(const float* __restrict__ emb, unsigned short* __restrict__ ehs_)
{
    __shared__ float tile[32][33];
    _Float16* ehs = (_Float16*)ehs_;
    int t  = threadIdx.x;
    int tx = t & 31, iy = t >> 5;
    int k0 = blockIdx.x * 32, d0 = blockIdx.y * 32;
#pragma unroll
    for (int j = 0; j < 4; ++j)
        tile[iy + 8 * j][tx] = emb[(size_t)(d0 + iy + 8 * j) * KCODE + k0 + tx];
    __syncthreads();
    // tile[d_off][k_off]; this thread emits code = k0+tx, d = d0 + iy*4 .. +3
    int code = k0 + tx;
    size_t base = (size_t)(((code >> 8) * 8) + (d0 >> 5)) * 8192 + (code & 255) * 32 + iy * 4;
    f16x4 h1, h2;
#pragma unroll
    for (int j = 0; j < 4; ++j) {
        float v = tile[iy * 4 + j][tx];
        _Float16 a = (_Float16)v;
        h1[j] = a;
        h2[j] = (_Float16)(v - (float)a);
    }
    *(f16x4*)(ehs + base)            = h1;
    *(f16x4*)(ehs + EH_PLANE + base) = h2;
}

// Argmin over codes via fp16x2-split MFMA.
// Block: 64 rows x full 4096 codes (16 tiles of 256; wave w owns codes w*64..+63).
// A planes in LDS (loaded once, single barrier); B fragments loaded DIRECTLY from
// global ehs (L2-resident, coalesced 1KB/instr) -> no Bh staging, no loop barriers.
__global__ __launch_bounds__(256, 2)
void k_argmin(const unsigned short* __restrict__ xh_, const unsigned short* __restrict__ ehs_,
              const float* __restrict__ e2, int* __restrict__ idx_out)
{
    __shared__ __align__(16) _Float16 Ah[2][64][256];   // 64 KB; XOR-swizzled 8-elem groups

    const _Float16* xh  = (const _Float16*)xh_;
    const _Float16* ehs = (const _Float16*)ehs_;

    const int t    = threadIdx.x;
    const int lane = t & 63, w = t >> 6;
    const int lo   = lane & 15, q = lane >> 4;
    const int row0 = blockIdx.x * 64;

    // ---- prologue: stage A planes from xh (rows m and m+32) ----
    {
        int m = t >> 3, kb = (t & 7) * 32;
#pragma unroll
        for (int p = 0; p < 2; ++p)
#pragma unroll
            for (int rr = 0; rr < 2; ++rr) {
                int mm = m + 32 * rr;
                const _Float16* src = xh + (size_t)p * XH_PLANE + (size_t)(row0 + mm) * DIM + kb;
#pragma unroll
                for (int g = 0; g < 4; ++g) {
                    f16x8 h = *(const f16x8*)(src + g * 8);
                    int grp = ((kb >> 3) + g) ^ (mm & 7);
                    *(f16x8*)&Ah[p][mm][grp * 8] = h;
                }
            }
    }
    __syncthreads();   // the ONLY barrier before the epilogue

    float best[16];
    int   bidx[16];
#pragma unroll
    for (int s = 0; s < 16; ++s) { best[s] = 3.4e38f; bidx[s] = 0; }

    // B fragment base for this lane: code-within-tile crow = w*64 + nf*16 + lo, d-off q*8
    const _Float16* ehp1 = ehs + (size_t)(w * 64 + lo) * 32 + q * 8;
    const _Float16* ehp2 = ehp1 + EH_PLANE;

    for (int ct = 0; ct < 16; ++ct) {
        f32x4 acc[4][4];
#pragma unroll
        for (int mf = 0; mf < 4; ++mf)
#pragma unroll
            for (int nf = 0; nf < 4; ++nf) acc[mf][nf] = (f32x4)0.0f;

        for (int ks = 0; ks < 8; ++ks) {
            const size_t so = (size_t)(ct * 8 + ks) * 8192;

            // A fragments via LDS (conflict-free b128 via XOR swizzle)
            int agrp = ((ks * 4 + q) ^ (lo & 7)) * 8;
            f16x8 a1[4], a2[4];
#pragma unroll
            for (int mf = 0; mf < 4; ++mf) {
                a1[mf] = *(const f16x8*)&Ah[0][mf * 16 + lo][agrp];
                a2[mf] = *(const f16x8*)&Ah[1][mf * 16 + lo][agrp];
            }

#pragma unroll
            for (int nf = 0; nf < 4; ++nf) {
                f16x8 b1 = *(const f16x8*)(ehp1 + so + nf * 512);
                f16x8 b2 = *(const f16x8*)(ehp2 + so + nf * 512);
#pragma unroll
                for (int mf = 0; mf < 4; ++mf) {
                    acc[mf][nf] = __builtin_amdgcn_mfma_f32_16x16x32_f16(a2[mf], b1, acc[mf][nf], 0, 0, 0);
                    acc[mf][nf] = __builtin_amdgcn_mfma_f32_16x16x32_f16(a1[mf], b2, acc[mf][nf], 0, 0, 0);
                    acc[mf][nf] = __builtin_amdgcn_mfma_f32_16x16x32_f16(a1[mf], b1, acc[mf][nf], 0, 0, 0);
                }
            }
        }

        // fold: dist = e2 - 2*score (x^2 row-constant dropped). codes ascending in ct,nf.
#pragma unroll
        for (int nf = 0; nf < 4; ++nf) {
            int cl = w * 64 + nf * 16 + lo;
            float e2v = e2[ct * 256 + cl];
#pragma unroll
            for (int mf = 0; mf < 4; ++mf)
#pragma unroll
                for (int r = 0; r < 4; ++r) {
                    float dist = fmaf(-2.0f, acc[mf][nf][r], e2v);
                    int s = mf * 4 + r;
                    if (dist < best[s]) { best[s] = dist; bidx[s] = ct * 256 + cl; }
                }
        }
    }

    // ---- final argmin reduction (scratch overlays Ah) ----
    __syncthreads();
    float* rv = (float*)&Ah[0][0][0];                 // [64 rows][64 slots]
    int*   ri = (int*)(((char*)&Ah[0][0][0]) + 16384);
#pragma unroll
    for (int s = 0; s < 16; ++s) {
        int row = (s >> 2) * 16 + q * 4 + (s & 3);    // mf*16 + q*4 + r
        rv[row * 64 + w * 16 + lo] = best[s];
        ri[row * 64 + w * 16 + lo] = bidx[s];
    }
    __syncthreads();
    if (t < 64) {
        float bv = rv[t * 64];
        int   bi = ri[t * 64];
        for (int j = 1; j < 64; ++j) {
            float v = rv[t * 64 + j];
            int  ii = ri[t * 64 + j];
            if (v < bv || (v == bv && ii < bi)) { bv = v; bi = ii; }
        }
        idx_out[row0 + t] = bi;
    }
}

// one wave per row: quantized copy (reconstructed from planes), loss, counts, dwT, idx
__global__ void k_gather(const float* __restrict__ x, const unsigned short* __restrict__ ehs_,
                         const int* __restrict__ idx, float* __restrict__ out_q,
                         float* __restrict__ out_idxf, float* __restrict__ counts,
                         float* __restrict__ dwT, float* __restrict__ lossp)
{
    const _Float16* ehs = (const _Float16*)ehs_;
    int t = threadIdx.x;
    int lane = t & 63, w = t >> 6;
    int n = blockIdx.x * 4 + w;
    int k = idx[n];
    float4 xv = *(const float4*)&x[(size_t)n * DIM + lane * 4];
    size_t base = (size_t)(((k >> 8) * 8) + (lane >> 3)) * 8192 + (k & 255) * 32 + (lane & 7) * 4;
    f16x4 h1 = *(const f16x4*)(ehs + base);
    f16x4 h2 = *(const f16x4*)(ehs + EH_PLANE + base);
    float4 ev;
    ev.x = (float)h1[0] + (float)h2[0];
    ev.y = (float)h1[1] + (float)h2[1];
    ev.z = (float)h1[2] + (float)h2[2];
    ev.w = (float)h1[3] + (float)h2[3];
    *(float4*)&out_q[(size_t)n * DIM + lane * 4] = ev;
    float dx = ev.x - xv.x, dy = ev.y - xv.y, dz = ev.z - xv.z, dw = ev.w - xv.w;
    float s = dx * dx + dy * dy + dz * dz + dw * dw;
#pragma unroll
    for (int off = 32; off > 0; off >>= 1) s += __shfl_down(s, off, 64);
    float* dp = &dwT[(size_t)k * DIM + lane * 4];
    atomicAdd(dp + 0, xv.x);
    atomicAdd(dp + 1, xv.y);
    atomicAdd(dp + 2, xv.z);
    atomicAdd(dp + 3, xv.w);
    if (lane == 0) {
        atomicAdd(&counts[k], 1.0f);
        atomicAdd(&lossp[blockIdx.x & 255], s);
        out_idxf[n] = (float)k;
    }
}

__global__ void k_finalize(const float* __restrict__ counts, const float* __restrict__ lossp,
                           const float* __restrict__ ema_counter,
                           const float* __restrict__ ema_cluster,
                           float* __restrict__ cnorm, float* __restrict__ scal,
                           float* __restrict__ out)
{
    __shared__ float red[256];
    int t = threadIdx.x;
    float ls = lossp[t];
    float ent = 0.0f, casum = 0.0f;
    float ca[16];
#pragma unroll
    for (int j = 0; j < 16; ++j) {
        int k = j * 256 + t;
        float c = counts[k];
        float p = c * (1.0f / 32768.0f);
        ent += p * logf(p + 1e-10f);
        ca[j] = ema_cluster[k] * 0.99f + c * 0.01f;   // cluster_hidden
        casum += ca[j];
    }
    red[t] = ls; __syncthreads();
    for (int o = 128; o > 0; o >>= 1) { if (t < o) red[t] += red[t + o]; __syncthreads(); }
    float loss_tot = red[0]; __syncthreads();
    red[t] = ent; __syncthreads();
    for (int o = 128; o > 0; o >>= 1) { if (t < o) red[t] += red[t + o]; __syncthreads(); }
    float ent_tot = red[0]; __syncthreads();
    red[t] = casum; __syncthreads();
    for (int o = 128; o > 0; o >>= 1) { if (t < o) red[t] += red[t + o]; __syncthreads(); }
    float casum_tot = red[0]; __syncthreads();

    float bias = 1.0f - powf(0.99f, ema_counter[0] + 1.0f);
    float n = casum_tot / bias;                 // sum(cluster_avg)
    float inv = n / (n + 4096.0f * 1e-5f);
#pragma unroll
    for (int j = 0; j < 16; ++j) {
        int k = j * 256 + t;
        cnorm[k] = (ca[j] / bias + 1e-5f) * inv;
    }
    if (t == 0) {
        out[OUT_LOSS] = 1.25f * loss_tot * (1.0f / (32768.0f * 256.0f));
        out[OUT_PERP] = expf(-ent_tot);
        scal[0] = bias;
    }
}

// new_embeddings[d][k] = (ema_dw*DECAY + dwT^T*(1-DECAY))/bias / cnorm[k]
__global__ void k_newemb(const float* __restrict__ dwT, const float* __restrict__ ema_dw,
                         const float* __restrict__ cnorm, const float* __restrict__ scal,
                         float* __restrict__ out_emb)
{
    __shared__ float tile[32][33];
    int t = threadIdx.x;
    int tx = t & 31, iy = t >> 5;
    int k0 = blockIdx.x * 32, d0 = blockIdx.y * 32;
#pragma unroll
    for (int j = 0; j < 4; ++j)
        tile[iy + 8 * j][tx] = dwT[(size_t)(k0 + iy + 8 * j) * DIM + d0 + tx];
    __syncthreads();
    float inv_bias = 1.0f / scal[0];
    float cn = cnorm[k0 + tx];
#pragma unroll
    for (int j = 0; j < 4; ++j) {
        int d = d0 + iy + 8 * j;
        float dwv = tile[tx][iy + 8 * j];
        float hid = ema_dw[(size_t)d * KCODE + k0 + tx] * 0.99f + dwv * 0.01f;
        out_emb[(size_t)d * KCODE + k0 + tx] = hid * inv_bias / cn;
    }
}

extern "C" void kernel_launch(void* const* d_in, const int* in_sizes, int n_in,
                              void* d_out, int out_size, void* d_ws, size_t ws_size,
                              hipStream_t stream)
{
    const float* x           = (const float*)d_in[0];
    const float* emb         = (const float*)d_in[1];
    const float* ema_counter = (const float*)d_in[2];
    const float* ema_cluster = (const float*)d_in[3];
    const float* ema_dw      = (const float*)d_in[4];
    float* out = (float*)d_out;
    float* ws  = (float*)d_ws;

    float* e2     = ws + WS_E2;
    float* counts = ws + WS_COUNTS;
    float* lossp  = ws + WS_LOSSP;
    float* scal   = ws + WS_SCAL;
    float* cnorm  = ws + WS_CNORM;
    int*   idxw   = (int*)(ws + WS_IDX);
    unsigned short* ehs = (unsigned short*)(ws + WS_EHS);
    float* dwT    = ws + WS_DWT;
    unsigned short* xh = (unsigned short*)(out + OUT_Q);  // scratch, overwritten by k_gather

    hipMemsetAsync(e2, 0, (size_t)WS_CNORM * sizeof(float), stream);
    hipMemsetAsync(dwT, 0, (size_t)KCODE * DIM * sizeof(float), stream);

    k_e2<<<dim3(16, 8), 256, 0, stream>>>(emb, e2);
    k_split_e<<<dim3(128, 8), 256, 0, stream>>>(emb, ehs);
    k_split_x<<<4096, 256, 0, stream>>>(x, xh);
    k_argmin<<<512, 256, 0, stream>>>(xh, ehs, e2, idxw);
    k_gather<<<8192, 256, 0, stream>>>(x, ehs, idxw, out + OUT_Q, out + OUT_IDX,
                                       counts, dwT, lossp);
    k_finalize<<<1, 256, 0, stream>>>(counts, lossp, ema_counter, ema_cluster,
                                      cnorm, scal, out);
    k_newemb<<<dim3(128, 8), 256, 0, stream>>>(dwT, ema_dw, cnorm, scal, out + OUT_EMB);
}